// Round 16
// baseline (86.549 us; speedup 1.0000x reference)
//
#include <hip/hip_runtime.h>
#include <hip/hip_bf16.h>
#include <stdint.h>

// BiLevelRoutingAttention (spiking LIF), T=4 B=2 L=8x32x32 C=256, fp32 I/O.
#define NT 4
#define NB 2
#define NW 32   // windows = 2*4*4
#define NS 256  // tokens/window = 4*8*8
#define NC 256
#define NH 8
#define ND 32
#define NK 4    // topk

typedef unsigned int u32;
typedef unsigned long long u64;
typedef unsigned short u16;
typedef __attribute__((ext_vector_type(8))) short bf16x8;
typedef __attribute__((ext_vector_type(4))) float f32x4;

// natural token index: tok = (t*NB+b)*8192 + Lt*1024 + Lh*32 + Lw
__device__ __forceinline__ int wofs(int w) {
  return (w >> 4) * 4096 + ((w >> 2) & 3) * 256 + (w & 3) * 8;
}
__device__ __forceinline__ int sofs(int s) {
  return ((s >> 6) << 10) + (((s >> 3) & 7) << 5) + (s & 7);
}
__device__ __forceinline__ size_t x_off(int t, int b, int w, int s, int c) {
  return ((size_t)((t * NB + b) * 8192 + wofs(w) + sofs(s))) * NC + c;
}

// fp32 -> bf16 round-to-nearest-even
__device__ __forceinline__ u32 f2bf(float f) {
  union { float f; u32 i; } u; u.f = f;
  return (u.i + 0x7FFFu + ((u.i >> 16) & 1u)) >> 16;
}

// async global(16B/lane) -> LDS (wave-uniform base + lane*16)
__device__ __forceinline__ void gload16(const u16* g, u16* l) {
  __builtin_amdgcn_global_load_lds(
      (const __attribute__((address_space(1))) void*)g,
      (__attribute__((address_space(3))) void*)l, 16, 0, 0);
}

// K1: w_qkv [256][768] fp32 -> bt [768][256] bf16 (transposed).
__global__ __launch_bounds__(256) void k_prepw(const float* __restrict__ w_qkv,
                                               u16* __restrict__ bt) {
  int n = blockIdx.x * 8 + (threadIdx.x >> 5);  // 0..767
  int kc = threadIdx.x & 31;                    // k-chunk of 8
  u16 vals[8];
#pragma unroll
  for (int j = 0; j < 8; ++j)
    vals[j] = (u16)f2bf(w_qkv[(size_t)(kc * 8 + j) * 768 + n]);
  *reinterpret_cast<uint4*>(&bt[(size_t)n * 256 + kc * 8]) =
      *reinterpret_cast<const uint4*>(vals);
}

// K2: fused MFMA GEMM. Each block owns a 128-row A-panel, full K=256 resident
// in LDS (converted fp32->bf16 ONCE, fused fp32 region sums), then loops
// nt=0,1,2 (q/k/v) streaming B tiles (BK=64 dbuf, gload_lds, counted vmcnt(4)
// flat 12-step pipeline). 8 waves (2Mx4N), per-wave 64x64, 16x16x32 bf16 MFMA.
// Spikes (>=2.0) -> bitmasks via __ballot + per-window flags.
__global__ __launch_bounds__(512, 2) void k_gemm(const float* __restrict__ x,
                                                 const u16* __restrict__ bt,
                                                 const float* __restrict__ b_qkv,
                                                 u32* __restrict__ qb, u32* __restrict__ kb,
                                                 u32* __restrict__ vb,
                                                 u32* __restrict__ winflag,
                                                 float* __restrict__ region) {
  __shared__ __align__(16) u16 As[128 * 256];    // 64 KB, K-resident
  __shared__ __align__(16) u16 Bs[2][256 * 64];  // 64 KB dbuf
  __shared__ u32 wfl3[3];

  const int tid = threadIdx.x;
  const int mt = blockIdx.x;  // 512 m-tiles of 128 tokens
  const int m0 = mt * 128;
  const int wave = tid >> 6, lane = tid & 63;
  const int wr = wave >> 2, wc = wave & 3;  // 2x4 waves of 64x64
  // window decomposition of this m-tile (128 consecutive tokens = 4 Lh rows)
  const int rb = (mt >> 6) & 1, tt = mt >> 7;
  const int v0 = (((mt >> 3) & 7) >> 2) * 16 + ((mt & 7) >> 1) * 4;

  if (tid < 3) wfl3[tid] = 0;

  // ---- A panel stage (once): fp32 -> bf16 swizzled LDS + fp32 region sums ----
  {
    const int g = wave;   // rows == g (mod 8); 16 rows/thread
    const int c4 = lane;  // float4 column (4 channels)
    float4 s[4];
#pragma unroll
    for (int ww = 0; ww < 4; ++ww) s[ww] = make_float4(0.f, 0.f, 0.f, 0.f);
#pragma unroll
    for (int p = 0; p < 16; ++p) {
      int row = p * 8 + g;
      float4 f = *reinterpret_cast<const float4*>(&x[(size_t)(m0 + row) * NC + c4 * 4]);
      int ww = p & 3;  // = (row&31)>>3
      s[ww].x += f.x; s[ww].y += f.y; s[ww].z += f.z; s[ww].w += f.w;
      uint2 bf;
      bf.x = f2bf(f.x) | (f2bf(f.y) << 16);
      bf.y = f2bf(f.z) | (f2bf(f.w) << 16);
      int slot = c4 >> 1, half = c4 & 1;
      int phys = slot ^ (row & 7);
      *reinterpret_cast<uint2*>(&As[row * 256 + phys * 8 + half * 4]) = bf;
    }
    float4* scratch = reinterpret_cast<float4*>(&Bs[0][0]);  // [4][8][64] f4 = 32 KB
#pragma unroll
    for (int ww = 0; ww < 4; ++ww) scratch[(ww * 8 + g) * 64 + c4] = s[ww];
  }
  __syncthreads();
  {
    const float* sp = reinterpret_cast<const float*>(&Bs[0][0]);
    for (int j = tid; j < 1024; j += 512) {
      int ww = j >> 8, c = j & 255;
      float ssum = 0.f;
#pragma unroll
      for (int g = 0; g < 8; ++g)
        ssum += sp[((ww * 8 + g) * 64 + (c >> 2)) * 4 + (c & 3)];
      atomicAdd(&region[(size_t)(rb * NW + v0 + ww) * NC + c], ssum * (1.0f / 1024.0f));
    }
  }
  __syncthreads();  // scratch reads done before B DMA overwrites Bs[0]

  const f32x4 vz = {0.f, 0.f, 0.f, 0.f};
  f32x4 acc[4][4];
#pragma unroll
  for (int m = 0; m < 4; ++m)
#pragma unroll
    for (int n = 0; n < 4; ++n) acc[m][n] = vz;

  // B stage for flat step s (nt = s>>2, kt = s&3): 4 gloads/thread
  auto stageB = [&](int buf, int s) {
    int n0 = (s >> 2) * 256, k0 = (s & 3) * 64;
#pragma unroll
    for (int i = 0; i < 4; ++i) {
      int c = i * 512 + tid;
      int row = c >> 3, p = c & 7;
      int sl = p ^ (row & 7);  // pre-swizzled source slot
      gload16(&bt[(size_t)(n0 + row) * 256 + k0 + sl * 8],
              &Bs[buf][(i * 512 + wave * 64) * 8]);
    }
  };

  stageB(0, 0);
  for (int s = 0; s < 12; ++s) {
    const int buf = s & 1;
    if (s < 11) {
      stageB(buf ^ 1, s + 1);  // next tile's loads stay in flight
      __builtin_amdgcn_sched_barrier(0);
      asm volatile("s_waitcnt vmcnt(4)" ::: "memory");  // step-s tile complete
    } else {
      __builtin_amdgcn_sched_barrier(0);
      asm volatile("s_waitcnt vmcnt(0)" ::: "memory");
    }
    __builtin_amdgcn_s_barrier();
    __builtin_amdgcn_sched_barrier(0);
    const int kt = s & 3;
#pragma unroll
    for (int kk = 0; kk < 2; ++kk) {
      bf16x8 af[4], bfr[4];
#pragma unroll
      for (int m = 0; m < 4; ++m) {
        int r = wr * 64 + m * 16 + (lane & 15);
        int slot = kt * 8 + kk * 4 + (lane >> 4);
        int phys = slot ^ (r & 7);
        af[m] = *reinterpret_cast<const bf16x8*>(&As[r * 256 + phys * 8]);
      }
#pragma unroll
      for (int n = 0; n < 4; ++n) {
        int r = wc * 64 + n * 16 + (lane & 15);
        int slot = kk * 4 + (lane >> 4);
        int phys = slot ^ (r & 7);
        bfr[n] = *reinterpret_cast<const bf16x8*>(&Bs[buf][r * 64 + phys * 8]);
      }
#pragma unroll
      for (int m = 0; m < 4; ++m)
#pragma unroll
        for (int n = 0; n < 4; ++n)
          acc[m][n] = __builtin_amdgcn_mfma_f32_16x16x32_bf16(af[m], bfr[n], acc[m][n], 0, 0, 0);
    }
    if (kt == 3) {
      // epilogue for nt = s>>2 (C/D: bit l -> row (l>>4)*4+r, col l&15)
      const int nt = s >> 2;
      u32* dst = (nt == 0) ? qb : (nt == 1) ? kb : vb;
      float bias[4];
#pragma unroll
      for (int n = 0; n < 4; ++n)
        bias[n] = b_qkv[nt * 256 + wc * 64 + n * 16 + (lane & 15)];
      const int g = lane >> 4;
      u32 wfl_loc = 0;
#pragma unroll
      for (int m = 0; m < 4; ++m)
#pragma unroll
        for (int r = 0; r < 4; ++r) {
          u32 words[2];
#pragma unroll
          for (int jp = 0; jp < 2; ++jp) {
            u64 b0 = __ballot(acc[m][2 * jp][r] + bias[2 * jp] >= 2.0f);
            u64 b1 = __ballot(acc[m][2 * jp + 1][r] + bias[2 * jp + 1] >= 2.0f);
            words[jp] = (u32)((b0 >> (g * 16)) & 0xFFFFu) |
                        ((u32)((b1 >> (g * 16)) & 0xFFFFu) << 16);
          }
          if ((lane & 15) < 2) {
            int jp = lane & 1;
            int row = wr * 64 + m * 16 + g * 4 + r;
            u32 wv = words[jp];
            dst[(size_t)(m0 + row) * NH + wc * 2 + jp] = wv;
            if (wv) wfl_loc |= 1u << ((row & 31) >> 3);  // ww class
          }
        }
      if (wfl_loc) atomicOr(&wfl3[nt], wfl_loc);
#pragma unroll
      for (int m = 0; m < 4; ++m)
#pragma unroll
        for (int n = 0; n < 4; ++n) acc[m][n] = vz;
    }
    __builtin_amdgcn_s_barrier();
  }

  __syncthreads();
  if (tid == 0) {
#pragma unroll
    for (int nt = 0; nt < 3; ++nt) {
      u32 f = wfl3[nt];
      if (f)
        for (int ww = 0; ww < 4; ++ww)
          if (f & (1u << ww))
            atomicOr(&winflag[(tt * NB + rb) * NW + v0 + ww], 1u << nt);
    }
  }
}

// K3: scores + top-4 (ties -> lower index, matching jax.lax.top_k)
__global__ __launch_bounds__(256) void k_scores(const float* __restrict__ region,
                                                int* __restrict__ idx) {
  __shared__ float rs[NW][NC];  // 32 KB
  __shared__ float scval[NW];
  int blk = blockIdx.x;  // 64 = b*32 + w
  int b = blk >> 5, w = blk & 31;
  int tid = threadIdx.x;
  for (int i = tid; i < NW * NC; i += 256)
    rs[i >> 8][i & 255] = region[(size_t)b * NW * NC + i];
  __syncthreads();
  int v = tid >> 3, l8 = tid & 7;
  float sum = 0.f;
  const float* a = rs[w];
  const float* bb = rs[v];
#pragma unroll
  for (int j = 0; j < 32; ++j) sum += a[l8 * 32 + j] * bb[l8 * 32 + j];
  sum += __shfl_xor(sum, 1);
  sum += __shfl_xor(sum, 2);
  sum += __shfl_xor(sum, 4);
  if (l8 == 0) scval[v] = sum * 0.17677669529663687f;  // 32^-0.5
  __syncthreads();
  if (tid == 0) {
    float sc[NW];
#pragma unroll
    for (int j = 0; j < NW; ++j) sc[j] = scval[j];
    for (int kk = 0; kk < NK; ++kk) {
      float best = -__builtin_inff(); int bi = 0;
      for (int j = 0; j < NW; ++j)
        if (sc[j] > best) { best = sc[j]; bi = j; }
      idx[(b * NW + w) * NK + kk] = bi;
      sc[bi] = -__builtin_inff();
    }
  }
}

// K4: attention + proj + window reverse; s-chunked 4x; fast path via window flags.
__global__ __launch_bounds__(256) void k_attn(const u32* __restrict__ qb,
                                              const u32* __restrict__ kb,
                                              const u32* __restrict__ vb,
                                              const int* __restrict__ idx,
                                              const u32* __restrict__ winflag,
                                              const float* __restrict__ w_proj,
                                              const float* __restrict__ b_proj,
                                              float* __restrict__ out) {
  __shared__ u32 qs[64 * NH];
  __shared__ unsigned short kvc[NH * ND * ND];
  __shared__ u32 ksum[NH * ND];
  __shared__ float attnrow[NC];

  int blk = blockIdx.x;  // 1024 = wid*4 + sc
  int wid = blk >> 2, sc = blk & 3;
  int t = wid >> 6, b = (wid >> 5) & 1, w = wid & 31;
  int s0 = sc * 64;
  int tid = threadIdx.x;

  u32 fs = winflag[(t * NB + b) * NW + w];
  int wj[NK];
  u32 fk = 0, fv = 0;
#pragma unroll
  for (int j = 0; j < NK; ++j) {
    wj[j] = idx[(b * NW + w) * NK + j];
    u32 f = winflag[(t * NB + b) * NW + wj[j]];
    fk |= f & 2u; fv |= f & 4u;
  }
  bool skip = !(fs & 1u) || !fk || !fv;

  if (skip) {
    float bp = b_proj[tid];
    for (int s = s0; s < s0 + 64; ++s) out[x_off(t, b, w, s, tid)] = bp;
    return;
  }

  // ---- exact integer slow path (only if spikes exist) ----
  int tb = (t * NB + b) * 8192;
  size_t gb[NK];
#pragma unroll
  for (int j = 0; j < NK; ++j) gb[j] = (size_t)(tb + wofs(wj[j])) * NH;
  size_t qbase = (size_t)(tb + wofs(w)) * NH;
  for (int i = tid; i < 64 * NH; i += 256)
    qs[i] = qb[qbase + (size_t)sofs(s0 + (i >> 3)) * NH + (i & 7)];
  {
    int h = tid >> 5, d = tid & 31;
    u32 cnt = 0;
    for (int n = 0; n < NK * NS; ++n)
      cnt += (kb[gb[n >> 8] + (size_t)sofs(n & 255) * NH + h] >> d) & 1u;
    ksum[tid] = cnt;
  }
  for (int p = tid; p < NH * ND * ND; p += 256) {
    int h = p >> 10, d = (p >> 5) & 31, e = p & 31;
    u32 cnt = 0;
    for (int n = 0; n < NK * NS; ++n) {
      size_t a = gb[n >> 8] + (size_t)sofs(n & 255) * NH + h;
      cnt += ((kb[a] >> d) & (vb[a] >> e)) & 1u;
    }
    kvc[p] = (unsigned short)cnt;
  }
  __syncthreads();
  int h = tid >> 5, e = tid & 31;
  float bpv = b_proj[tid];
  for (int sl = 0; sl < 64; ++sl) {
    u32 qw = qs[sl * NH + h];
    float num = 0.f, den = 0.f;
    for (int d = 0; d < ND; ++d) {
      if ((qw >> d) & 1u) {
        den += (float)ksum[h * ND + d];
        num += (float)kvc[h * ND * ND + d * ND + e];
      }
    }
    attnrow[tid] = num / (den + 1e-6f);
    __syncthreads();
    float acc = bpv;
    for (int c = 0; c < NC; ++c) acc += attnrow[c] * w_proj[c * NC + tid];
    out[x_off(t, b, w, s0 + sl, tid)] = acc;
    __syncthreads();
  }
}

extern "C" void kernel_launch(void* const* d_in, const int* in_sizes, int n_in,
                              void* d_out, int out_size, void* d_ws, size_t ws_size,
                              hipStream_t stream) {
  const float* x      = (const float*)d_in[0];
  const float* w_qkv  = (const float*)d_in[1];
  const float* b_qkv  = (const float*)d_in[2];
  const float* w_proj = (const float*)d_in[3];
  const float* b_proj = (const float*)d_in[4];
  float* out = (float*)d_out;

  char* ws = (char*)d_ws;
  int* idx       = (int*)(ws + 0x200000);         // 1 KB
  u16* bt        = (u16*)(ws + 0x201000);         // 384 KB bf16 [768][256]
  u32* winflag   = (u32*)(ws + 0x270000);         // 1 KB (t,b,w): bit0 q, bit1 k, bit2 v
  float* region  = (float*)(ws + 0x271000);       // 64 KB [b][v][c]
  u32* qb        = (u32*)(ws + 0x300000);         // 2 MB each, natural token order
  u32* kb        = qb + (size_t)NT * NB * NW * NS * NH;
  u32* vb        = kb + (size_t)NT * NB * NW * NS * NH;

  (void)hipMemsetAsync(ws + 0x270000, 0, 0x11000, stream);  // winflag + region
  k_prepw<<<96, 256, 0, stream>>>(w_qkv, bt);
  k_gemm<<<512, 512, 0, stream>>>(x, bt, b_qkv, qb, kb, vb, winflag, region);
  k_scores<<<NB * NW, 256, 0, stream>>>(region, idx);
  k_attn<<<NT * NB * NW * 4, 256, 0, stream>>>(qb, kb, vb, idx, winflag, w_proj, b_proj, out);
}